// Round 3
// baseline (258.052 us; speedup 1.0000x reference)
//
#include <hip/hip_runtime.h>
#include <hip/hip_bf16.h>
#include <stdint.h>

typedef __bf16 bf16;
typedef __bf16 bf16x4 __attribute__((ext_vector_type(4)));
typedef __bf16 bf16x8 __attribute__((ext_vector_type(8)));
typedef float f32x4 __attribute__((ext_vector_type(4)));

#define GLOBAL_AS __attribute__((address_space(1)))
#define LDS_AS __attribute__((address_space(3)))

__device__ __forceinline__ void g2lds16(const bf16* g, bf16* l) {
  // async global->LDS DMA, 16 B/lane; LDS dest = wave-uniform base + lane*16
  __builtin_amdgcn_global_load_lds((const GLOBAL_AS void*)g, (LDS_AS void*)l, 16, 0, 0);
}

// ---------------------------------------------------------------------------
// Kernel 1: pure streaming RMSNorm (F.normalize * sqrt(1024) * gamma).
// ---------------------------------------------------------------------------
__global__ __launch_bounds__(256) void rmsnorm_kernel(
    const float* __restrict__ x, const float* __restrict__ gamma,
    bf16* __restrict__ xn) {
  __shared__ float wss[4];
  const int t = threadIdx.x;
  const size_t row = blockIdx.x;
  const float* xr = x + row * 1024;

  float4 xv = *(const float4*)&xr[t * 4];
  float v[4] = {xv.x, xv.y, xv.z, xv.w};
  float ss = v[0]*v[0] + v[1]*v[1] + v[2]*v[2] + v[3]*v[3];
#pragma unroll
  for (int mm = 1; mm < 64; mm <<= 1) ss += __shfl_xor(ss, mm);
  if ((t & 63) == 0) wss[t >> 6] = ss;
  __syncthreads();
  ss = wss[0] + wss[1] + wss[2] + wss[3];
  float inv = 32.0f / sqrtf(fmaxf(ss, 1e-24f));  // sqrt(1024)=32

  float4 gv = *(const float4*)&gamma[t * 4];
  float gvv[4] = {gv.x, gv.y, gv.z, gv.w};
  bf16x4 outv;
#pragma unroll
  for (int i = 0; i < 4; ++i) outv[i] = (bf16)(v[i] * inv * gvv[i]);
  *(bf16x4*)&xn[row * 1024 + t * 4] = outv;
}

// ---------------------------------------------------------------------------
// Kernel 2: fp32 -> bf16 transpose (for B^T GEMM operand), 32x32 tiles
// ---------------------------------------------------------------------------
__global__ void transpose_f32_bf16(const float* __restrict__ in, bf16* __restrict__ out,
                                   int R, int C) {
  __shared__ bf16 tile[32][33];
  const int tx = threadIdx.x, ty = threadIdx.y;  // 32 x 8
  const int c0 = blockIdx.x * 32, r0 = blockIdx.y * 32;
#pragma unroll
  for (int i = 0; i < 32; i += 8)
    tile[ty + i][tx] = (bf16)in[(size_t)(r0 + ty + i) * C + c0 + tx];
  __syncthreads();
#pragma unroll
  for (int i = 0; i < 32; i += 8)
    out[(size_t)(c0 + ty + i) * R + r0 + tx] = tile[tx][ty + i];
}

// Wg [1024,16] -> rows 3072..3087 of BtAug [3200,1024]. Tiny (16K elements).
__global__ __launch_bounds__(256) void wg_transpose(const float* __restrict__ Wg,
                                                    bf16* __restrict__ BtAug) {
  int idx = blockIdx.x * 256 + threadIdx.x;   // [0, 16384)
  int n = idx >> 10, k = idx & 1023;
  BtAug[(size_t)(3072 + n) * 1024 + k] = (bf16)Wg[(size_t)k * 16 + n];
}

// ---------------------------------------------------------------------------
// Kernel 3a: MFMA bf16 GEMM, 128x128 tile, BK=64, 2-barrier structure.
// Kept for the output GEMM (N=1024: 512-block grid balances the GPU).
// ---------------------------------------------------------------------------
template <typename OutT>
__global__ __launch_bounds__(256) void gemm_bt_128(
    const bf16* __restrict__ A, const bf16* __restrict__ Bt,
    OutT* __restrict__ C, int M, int N, int K) {
  __shared__ bf16 lA[128 * 64];
  __shared__ bf16 lB[128 * 64];
  const int t = threadIdx.x;
  const int w = t >> 6, lane = t & 63;
  const int col0 = lane & 15, quad = lane >> 4;
  const int m0 = blockIdx.y * 128, n0 = blockIdx.x * 128;
  const int wr = (w >> 1) * 64, wc = (w & 1) * 64;

  const int lrow = t >> 3;                          // 0..31 (includes w*8)
  const int sswz = (((t & 7) ^ (lrow & 7)) << 3);   // swizzled src k-offset

  f32x4 acc[4][4] = {};

  for (int k0 = 0; k0 < K; k0 += 64) {
    __syncthreads();  // previous iteration's LDS reads done
#pragma unroll
    for (int c = 0; c < 4; ++c) {
      g2lds16(A  + (size_t)(m0 + c * 32 + lrow) * K + k0 + sswz, &lA[c * 2048 + w * 512]);
      g2lds16(Bt + (size_t)(n0 + c * 32 + lrow) * K + k0 + sswz, &lB[c * 2048 + w * 512]);
    }
    __syncthreads();  // drains vmcnt(0): staged tiles visible

#pragma unroll
    for (int kh = 0; kh < 2; ++kh) {
      bf16x8 af[4], bfr[4];
#pragma unroll
      for (int i = 0; i < 4; ++i) {
        int row = wr + i * 16 + col0;
        af[i] = *(const bf16x8*)&lA[row * 64 + (((kh * 4 + quad) ^ (row & 7)) << 3)];
      }
#pragma unroll
      for (int j = 0; j < 4; ++j) {
        int row = wc + j * 16 + col0;
        bfr[j] = *(const bf16x8*)&lB[row * 64 + (((kh * 4 + quad) ^ (row & 7)) << 3)];
      }
#pragma unroll
      for (int i = 0; i < 4; ++i)
#pragma unroll
        for (int j = 0; j < 4; ++j)
          acc[i][j] = __builtin_amdgcn_mfma_f32_16x16x32_bf16(af[i], bfr[j], acc[i][j], 0, 0, 0);
    }
  }

#pragma unroll
  for (int i = 0; i < 4; ++i)
#pragma unroll
    for (int j = 0; j < 4; ++j)
#pragma unroll
      for (int r = 0; r < 4; ++r) {
        int row = m0 + wr + i * 16 + quad * 4 + r;
        int col = n0 + wc + j * 16 + col0;
        C[(size_t)row * N + col] = (OutT)acc[i][j][r];
      }
}

// ---------------------------------------------------------------------------
// Kernel 3b: 256x256 GEMM, 512 threads = 8 waves (2Mx4N), BK=64, 128 KB LDS
// double buffer.
//
// R2 post-mortem: the 8-barrier-per-tile phase structure fully SERIALIZED
// LDS reads and MFMA (per-tile: 750 ds_read + 250 stage-write + 620 MFMA
// cyc = 1620 serial; measured 1640). Fix: ds_reads of a stable buffer need
// NO cross-wave sync -- barriers only guard the staging<->read handoff.
// v3 tile body (2 barriers + 2 counted vmcnt per K-tile, never vmcnt(0)):
//   vmcnt(4)   // B of this tile landed (my 4 oldest of 8 outstanding)
//   barrier    // -> B readable by all waves
//   read all 8 bv fragments (held in regs for whole tile)
//   issue 8 staging loads for tile t+1: b0..b3 then a0..a3 (ledger order)
//   vmcnt(8)   // outstanding 12 -> drain 4 = A of this tile landed
//   barrier    // -> A readable
//   4 x { read 4 af ; 16 MFMA }   // straight-line, compiler-counted lgkmcnt
//                                 // -> af reads overlap MFMA (the R2 fix)
// Cross-wave hazards: (RAW) my staged writes drained by my vmcnt before the
// barrier; readers read after it. (WAR) staging into buffer X during tile t
// overwrites tile t-1 data; every wave's t-1 reads completed (lgkmcnt before
// its MFMAs) before it passed tile t's first barrier, which precedes my
// store issues. Prologue issues tile0's 8 loads (b first) -> loop invariant
// "8 outstanding at tile top" holds from i=0.
// Swizzle: LDS[row][ck] = G[row][ck^(row&7)] via pre-swizzled global source
// (linear LDS dest, rule #21); reads XOR the same involution. 0-conflict.
// Partial last column tile (N=3200): B staging rows clamp to N-1 (zero pad
// rows), C stores guarded col<N.
// ---------------------------------------------------------------------------
template <typename OutT>
__global__ __launch_bounds__(512, 2) void gemm_bt_256(
    const bf16* __restrict__ A, const bf16* __restrict__ Bt,
    OutT* __restrict__ C, int M, int N, int K) {
  extern __shared__ bf16 lds[];
  bf16* A0 = lds;               // [256][64]
  bf16* B0 = lds + 16384;
  bf16* A1 = lds + 32768;
  bf16* B1 = lds + 49152;

  const int t = threadIdx.x;
  const int w = t >> 6, lane = t & 63;
  const int wm = w >> 2, wn = w & 3;
  const int col0 = lane & 15, quad = lane >> 4;
  const int s_sub = lane >> 3;                    // row within wave's 8-row span
  const int sswz = (((lane & 7) ^ s_sub) << 3);   // pre-swizzled src 16B chunk

  // XCD-aware bijective swizzle (requires nwg % 8 == 0; 416 is)
  int nwg = gridDim.x * gridDim.y;
  int bid = blockIdx.y * gridDim.x + blockIdx.x;
  int swz = bid;
  if ((nwg & 7) == 0) swz = (bid & 7) * (nwg >> 3) + (bid >> 3);
  const int n0 = (swz % gridDim.x) * 256;
  const int m0 = (swz / gridDim.x) * 256;

  const bf16* Abase = A + (size_t)m0 * (size_t)K;

  auto stageA = [&](int ks, int c, bf16* dstA) {
    // chunk c covers rows {c*32..+31} (waves 0-3) u {128+c*32..+31} (waves 4-7)
    int rb = (w < 4) ? (c * 32 + w * 8) : (128 + c * 32 + (w - 4) * 8);
    g2lds16(Abase + (size_t)(rb + s_sub) * K + ks + sswz, dstA + rb * 64);
  };
  auto stageB = [&](int ks, int c, bf16* dstB) {
    int rb = c * 64 + w * 8;
    int gr = n0 + rb + s_sub;
    gr = (gr < N) ? gr : (N - 1);   // clamp: partial tile reads zero-pad row
    g2lds16(Bt + (size_t)gr * (size_t)K + ks + sswz, dstB + rb * 64);
  };

  f32x4 acc[8][4] = {};
  const int NT = K >> 6;   // K-tiles (16 for K=1024)
  const int NI = NT >> 1;

  // ---- prologue: issue tile 0's 8 loads, B first (matches ledger)
#pragma unroll
  for (int c = 0; c < 4; ++c) stageB(0, c, B0);
#pragma unroll
  for (int c = 0; c < 4; ++c) stageA(0, c, A0);

  for (int i = 0; i < NI; ++i) {
#pragma unroll
    for (int h = 0; h < 2; ++h) {
      bf16* cA = h ? A1 : A0;   // compute buffers (tile 2i+h)
      bf16* cB = h ? B1 : B0;
      bf16* nA = h ? A0 : A1;   // stage targets (tile 2i+h+1)
      bf16* nB = h ? B0 : B1;
      int tn = 2 * i + h + 1;
      int kn = ((tn < NT) ? tn : 0) << 6;  // clamp: tail garbage never read

      // B of this tile landed (4 oldest of my 8 outstanding loads)
      asm volatile("s_waitcnt vmcnt(4)" ::: "memory");
      __builtin_amdgcn_s_barrier();

      // read ALL B fragments (held in regs across the tile)
      bf16x8 bv[4][2];
#pragma unroll
      for (int nj = 0; nj < 4; ++nj) {
        int br = wn * 64 + nj * 16 + col0;
#pragma unroll
        for (int ks = 0; ks < 2; ++ks)
          bv[nj][ks] = *(const bf16x8*)&cB[br * 64 + (((ks * 4 + quad) ^ (br & 7)) << 3)];
      }

      // stage ALL of tile t+1 into the other buffer: B first, A last
      stageB(kn, 0, nB); stageB(kn, 1, nB); stageB(kn, 2, nB); stageB(kn, 3, nB);
      stageA(kn, 0, nA); stageA(kn, 1, nA); stageA(kn, 2, nA); stageA(kn, 3, nA);

      // A of this tile landed (outstanding 12 -> drain 4 oldest = my a0..a3)
      asm volatile("s_waitcnt vmcnt(8)" ::: "memory");
      __builtin_amdgcn_s_barrier();

      // 4 chunks: {read 4 af, 16 MFMA} straight-line; compiler interleaves
      // ds_read and MFMA with counted lgkmcnt -> reads overlap compute.
#pragma unroll
      for (int p = 0; p < 4; ++p) {
        bf16x8 af[2][2];
#pragma unroll
        for (int m2 = 0; m2 < 2; ++m2) {
          int ar = wm * 128 + (p * 2 + m2) * 16 + col0;
#pragma unroll
          for (int ks = 0; ks < 2; ++ks)
            af[m2][ks] = *(const bf16x8*)&cA[ar * 64 + (((ks * 4 + quad) ^ (ar & 7)) << 3)];
        }
        __builtin_amdgcn_s_setprio(1);
#pragma unroll
        for (int ks = 0; ks < 2; ++ks)
#pragma unroll
          for (int m2 = 0; m2 < 2; ++m2)
#pragma unroll
            for (int nj = 0; nj < 4; ++nj)
              acc[p * 2 + m2][nj] = __builtin_amdgcn_mfma_f32_16x16x32_bf16(
                  af[m2][ks], bv[nj][ks], acc[p * 2 + m2][nj], 0, 0, 0);
        __builtin_amdgcn_s_setprio(0);
      }
    }
  }
  // drain tail garbage stages before wave exit (LDS could be reassigned)
  asm volatile("s_waitcnt vmcnt(0)" ::: "memory");

  // epilogue: C/D layout col=lane&15, row=quad*4+r
#pragma unroll
  for (int mi = 0; mi < 8; ++mi)
#pragma unroll
    for (int nj = 0; nj < 4; ++nj) {
      int col = n0 + wn * 64 + nj * 16 + col0;
      if (col < N) {
        size_t base = (size_t)(m0 + wm * 128 + mi * 16 + quad * 4) * N + col;
#pragma unroll
        for (int r = 0; r < 4; ++r)
          C[base + (size_t)r * N] = (OutT)acc[mi][nj][r];
      }
    }
}

// ---------------------------------------------------------------------------
// Kernel 4: sliding-window attention, one block per (b, h, 64-query group).
// ---------------------------------------------------------------------------
#define NEG_BIG -1e30f
__global__ __launch_bounds__(256) void attn_kernel(
    const bf16* __restrict__ qkv, const float* __restrict__ bg,
    bf16* __restrict__ attnO) {
  __shared__ bf16 lQ[64 * 64];     // 8 KB,  swizzled chunks
  __shared__ bf16 lKV[320 * 64];   // 40 KB: K[320][64] phase1, Vt[64][320] phase2
  __shared__ bf16 lP[4 * 16 * 32]; // 4 KB: per-wave P C->A layout scratch

  const int t = threadIdx.x;
  const int w = t >> 6, lane = t & 63;
  const int col0 = lane & 15, quad = lane >> 4;

  const int blk = blockIdx.x;
  const int g = blk & 63;
  const int h = (blk >> 6) & 15;
  const int bb = blk >> 10;
  const int qs = g * 64;

  const size_t rs = 3200;
  const bf16* qbase = qkv + ((size_t)bb * 4096) * rs + h * 64;

  // stage Q [64][64], chunk-swizzled: LDS[row][ck^(row&7)] = G[row][ck]
  for (int c = t; c < 64 * 8; c += 256) {
    int row = c >> 3, ck = c & 7;
    *(uint4*)&lQ[row * 64 + ((ck ^ (row & 7)) << 3)] =
        *(const uint4*)(qbase + (size_t)(qs + row) * rs + ck * 8);
  }
  // stage K [320][64], chunk-swizzled (zero-fill j<0)
  for (int c = t; c < 320 * 8; c += 256) {
    int row = c >> 3, ck = c & 7;
    int j = qs - 256 + row;
    uint4 val = {0, 0, 0, 0};
    if (j >= 0) val = *(const uint4*)(qbase + 1024 + (size_t)j * rs + ck * 8);
    *(uint4*)&lKV[row * 64 + ((ck ^ (row & 7)) << 3)] = val;
  }
  __syncthreads();

  // QK^T: wave w owns queries [w*16, w*16+16); S tile per wave: [16, 320]
  const int qrow = w * 16 + col0;
  bf16x8 a0 = *(const bf16x8*)&lQ[qrow * 64 + ((quad ^ (qrow & 7)) << 3)];
  bf16x8 a1 = *(const bf16x8*)&lQ[qrow * 64 + (((4 + quad) ^ (qrow & 7)) << 3)];
  f32x4 s[20];
#pragma unroll
  for (int kt = 0; kt < 20; ++kt) {
    int krow = kt * 16 + col0;
    bf16x8 b0 = *(const bf16x8*)&lKV[krow * 64 + ((quad ^ (krow & 7)) << 3)];
    bf16x8 b1 = *(const bf16x8*)&lKV[krow * 64 + (((4 + quad) ^ (krow & 7)) << 3)];
    f32x4 z = {};
    z = __builtin_amdgcn_mfma_f32_16x16x32_bf16(a0, b0, z, 0, 0, 0);
    z = __builtin_amdgcn_mfma_f32_16x16x32_bf16(a1, b1, z, 0, 0, 0);
    s[kt] = z;
  }
  __syncthreads();  // all waves done reading K from lKV

  // stage V transposed Vt[d][c] over lKV, key-major lanes + chunk swizzle
  {
    const int jl = t & 31, dg = t >> 5;
#pragma unroll
    for (int cc = 0; cc < 10; ++cc) {
      int j = qs - 256 + cc * 32 + jl;
      bf16 tmp[8];
      if (j >= 0) {
        *(uint4*)tmp = *(const uint4*)(qbase + 2048 + (size_t)j * rs + dg * 8);
      } else {
#pragma unroll
        for (int d2 = 0; d2 < 8; ++d2) tmp[d2] = (bf16)0.f;
      }
      int ck = cc * 4 + (jl >> 3);     // 16B chunk index along keys (0..39)
      int wi = jl & 7;                 // element within chunk
#pragma unroll
      for (int d2 = 0; d2 < 8; ++d2) {
        int d = dg * 8 + d2;
        lKV[d * 320 + ((ck ^ (d & 7)) << 3) + wi] = tmp[d2];
      }
    }
  }

  // softmax in registers (C layout: query row = quad*4+r, key col = kt*16+col0)
  float mrow[4] = {NEG_BIG, NEG_BIG, NEG_BIG, NEG_BIG};
  float lrow[4] = {0, 0, 0, 0};
#pragma unroll
  for (int kt = 0; kt < 20; ++kt) {
    int c = kt * 16 + col0;
#pragma unroll
    for (int r = 0; r < 4; ++r) {
      int ql = w * 16 + quad * 4 + r;
      bool valid = (c >= ql) && (c <= ql + 256) && (qs - 256 + c >= 0);
      float sv = valid ? s[kt][r] * 0.125f : NEG_BIG;  // scale = 1/sqrt(64)
      s[kt][r] = sv;
      mrow[r] = fmaxf(mrow[r], sv);
    }
  }
#pragma unroll
  for (int mm = 1; mm < 16; mm <<= 1)
#pragma unroll
    for (int r = 0; r < 4; ++r) mrow[r] = fmaxf(mrow[r], __shfl_xor(mrow[r], mm));
#pragma unroll
  for (int kt = 0; kt < 20; ++kt)
#pragma unroll
    for (int r = 0; r < 4; ++r) {
      float p = __expf(s[kt][r] - mrow[r]);
      s[kt][r] = p;
      lrow[r] += p;
    }
#pragma unroll
  for (int mm = 1; mm < 16; mm <<= 1)
#pragma unroll
    for (int r = 0; r < 4; ++r) lrow[r] += __shfl_xor(lrow[r], mm);

  __syncthreads();  // Vt staged

  // PV: per 32-key chunk, C->A transpose of P through per-wave LDS scratch.
  f32x4 o[4] = {};
  bf16* pw = &lP[w * 512];
#pragma unroll
  for (int kc = 0; kc < 10; ++kc) {
#pragma unroll
    for (int r = 0; r < 4; ++r) {
      pw[(quad * 4 + r) * 32 + col0]      = (bf16)s[2 * kc][r];
      pw[(quad * 4 + r) * 32 + 16 + col0] = (bf16)s[2 * kc + 1][r];
    }
    asm volatile("s_waitcnt lgkmcnt(0)" ::: "memory");
    bf16x8 pa = *(const bf16x8*)&pw[col0 * 32 + quad * 8];
#pragma unroll
    for (int n = 0; n < 4; ++n) {
      int d = n * 16 + col0;
      bf16x8 bvv = *(const bf16x8*)&lKV[d * 320 + (((kc * 4 + quad) ^ (d & 7)) << 3)];
      o[n] = __builtin_amdgcn_mfma_f32_16x16x32_bf16(pa, bvv, o[n], 0, 0, 0);
    }
  }

  // epilogue: divide by l, apply sigmoid(gate_logit + bg[h]), write [b,s,h*64+d]
  const bf16* gbase = qkv + ((size_t)bb * 4096) * rs + 3072 + h;
  const float bgh = bg[h];
#pragma unroll
  for (int r = 0; r < 4; ++r) {
    int ql = w * 16 + quad * 4 + r;
    int srow = qs + ql;
    float logit = (float)gbase[(size_t)srow * rs] + bgh;
    float gate = 1.f / (1.f + __expf(-logit));
    float scale = gate / lrow[r];
#pragma unroll
    for (int n = 0; n < 4; ++n)
      attnO[((size_t)bb * 4096 + srow) * 1024 + h * 64 + n * 16 + col0] =
          (bf16)(o[n][r] * scale);
  }
}

// ---------------------------------------------------------------------------
extern "C" void kernel_launch(void* const* d_in, const int* in_sizes, int n_in,
                              void* d_out, int out_size, void* d_ws, size_t ws_size,
                              hipStream_t stream) {
  const float *x = nullptr, *gamma = nullptr, *Wqkv = nullptr,
              *Wg = nullptr, *bg = nullptr, *Wout = nullptr;
  for (int i = 0; i < n_in; ++i) {
    switch (in_sizes[i]) {
      case 8388608: x     = (const float*)d_in[i]; break;
      case 1024:    gamma = (const float*)d_in[i]; break;
      case 3145728: Wqkv  = (const float*)d_in[i]; break;
      case 16384:   Wg    = (const float*)d_in[i]; break;
      case 16:      bg    = (const float*)d_in[i]; break;
      case 1048576: Wout  = (const float*)d_in[i]; break;
    }
  }
  float* out = (float*)d_out;  // fp32 output

  // one-time: allow 128 KB dynamic LDS for the 256^2 GEMM
  static bool attr_done = false;
  if (!attr_done) {
    hipFuncSetAttribute(reinterpret_cast<const void*>(&gemm_bt_256<bf16>),
                        hipFuncAttributeMaxDynamicSharedMemorySize, 131072);
    attr_done = true;
  }

  // BtAug = [WqkvT (3072 rows); WgT (16 rows); zero pad (112 rows)] x 1024
  char* ws = (char*)d_ws;
  bf16* qkv   = (bf16*)ws;  ws += (size_t)8192 * 3200 * 2;   // 52.4 MB (incl. gate logits)
  bf16* xn    = (bf16*)ws;                                    // 16 MB, dead after QKV GEMM
  bf16* attnO = (bf16*)ws;  ws += (size_t)8192 * 1024 * 2;   // aliases xn (stream-ordered)
  bf16* BtAug = (bf16*)ws;  ws += (size_t)3200 * 1024 * 2;   // 6.55 MB
  bf16* WoutT = (bf16*)ws;  ws += (size_t)1024 * 1024 * 2;   // total ~77.9 MB

  // zero the 112 pad rows of BtAug (re-poisoned to 0xAA before every call)
  hipMemsetAsync(BtAug + (size_t)3088 * 1024, 0, (size_t)112 * 1024 * 2, stream);

  rmsnorm_kernel<<<8192, 256, 0, stream>>>(x, gamma, xn);
  transpose_f32_bf16<<<dim3(3072 / 32, 1024 / 32), dim3(32, 8), 0, stream>>>(Wqkv, BtAug, 1024, 3072);
  wg_transpose<<<64, 256, 0, stream>>>(Wg, BtAug);
  transpose_f32_bf16<<<dim3(1024 / 32, 1024 / 32), dim3(32, 8), 0, stream>>>(Wout, WoutT, 1024, 1024);
  // QKV GEMM: 256^2, grid 13x32 = 416 (nwg%8==0 -> XCD swizzle valid)
  gemm_bt_256<bf16><<<dim3(13, 32), 512, 131072, stream>>>(xn, BtAug, qkv, 8192, 3200, 1024);
  attn_kernel<<<2048, 256, 0, stream>>>(qkv, bg, attnO);
  gemm_bt_128<float><<<dim3(1024 / 128, 8192 / 128), 256, 0, stream>>>(attnO, WoutT, out, 8192, 1024, 1024);
}

// Round 4
// 257.536 us; speedup vs baseline: 1.0020x; 1.0020x over previous
//
#include <hip/hip_runtime.h>
#include <hip/hip_bf16.h>
#include <stdint.h>

typedef __bf16 bf16;
typedef __bf16 bf16x4 __attribute__((ext_vector_type(4)));
typedef __bf16 bf16x8 __attribute__((ext_vector_type(8)));
typedef float f32x4 __attribute__((ext_vector_type(4)));

#define GLOBAL_AS __attribute__((address_space(1)))
#define LDS_AS __attribute__((address_space(3)))

__device__ __forceinline__ void g2lds16(const bf16* g, bf16* l) {
  // async global->LDS DMA, 16 B/lane; LDS dest = wave-uniform base + lane*16
  __builtin_amdgcn_global_load_lds((const GLOBAL_AS void*)g, (LDS_AS void*)l, 16, 0, 0);
}

// ---------------------------------------------------------------------------
// Kernel 1: pure streaming RMSNorm (F.normalize * sqrt(1024) * gamma).
// ---------------------------------------------------------------------------
__global__ __launch_bounds__(256) void rmsnorm_kernel(
    const float* __restrict__ x, const float* __restrict__ gamma,
    bf16* __restrict__ xn) {
  __shared__ float wss[4];
  const int t = threadIdx.x;
  const size_t row = blockIdx.x;
  const float* xr = x + row * 1024;

  float4 xv = *(const float4*)&xr[t * 4];
  float v[4] = {xv.x, xv.y, xv.z, xv.w};
  float ss = v[0]*v[0] + v[1]*v[1] + v[2]*v[2] + v[3]*v[3];
#pragma unroll
  for (int mm = 1; mm < 64; mm <<= 1) ss += __shfl_xor(ss, mm);
  if ((t & 63) == 0) wss[t >> 6] = ss;
  __syncthreads();
  ss = wss[0] + wss[1] + wss[2] + wss[3];
  float inv = 32.0f / sqrtf(fmaxf(ss, 1e-24f));  // sqrt(1024)=32

  float4 gv = *(const float4*)&gamma[t * 4];
  float gvv[4] = {gv.x, gv.y, gv.z, gv.w};
  bf16x4 outv;
#pragma unroll
  for (int i = 0; i < 4; ++i) outv[i] = (bf16)(v[i] * inv * gvv[i]);
  *(bf16x4*)&xn[row * 1024 + t * 4] = outv;
}

// ---------------------------------------------------------------------------
// Kernel 2: fp32 -> bf16 transpose (for B^T GEMM operand), 32x32 tiles
// ---------------------------------------------------------------------------
__global__ void transpose_f32_bf16(const float* __restrict__ in, bf16* __restrict__ out,
                                   int R, int C) {
  __shared__ bf16 tile[32][33];
  const int tx = threadIdx.x, ty = threadIdx.y;  // 32 x 8
  const int c0 = blockIdx.x * 32, r0 = blockIdx.y * 32;
#pragma unroll
  for (int i = 0; i < 32; i += 8)
    tile[ty + i][tx] = (bf16)in[(size_t)(r0 + ty + i) * C + c0 + tx];
  __syncthreads();
#pragma unroll
  for (int i = 0; i < 32; i += 8)
    out[(size_t)(c0 + ty + i) * R + r0 + tx] = tile[tx][ty + i];
}

// Wg [1024,16] -> rows 3072..3087 of BtAug [3200,1024]. Tiny (16K elements).
__global__ __launch_bounds__(256) void wg_transpose(const float* __restrict__ Wg,
                                                    bf16* __restrict__ BtAug) {
  int idx = blockIdx.x * 256 + threadIdx.x;   // [0, 16384)
  int n = idx >> 10, k = idx & 1023;
  BtAug[(size_t)(3072 + n) * 1024 + k] = (bf16)Wg[(size_t)k * 16 + n];
}

// ---------------------------------------------------------------------------
// Kernel 3a: MFMA bf16 GEMM, 128x128 tile, BK=64, 2-barrier structure.
// Kept for the output GEMM (N=1024: 512-block grid balances the GPU).
// ---------------------------------------------------------------------------
template <typename OutT>
__global__ __launch_bounds__(256) void gemm_bt_128(
    const bf16* __restrict__ A, const bf16* __restrict__ Bt,
    OutT* __restrict__ C, int M, int N, int K) {
  __shared__ bf16 lA[128 * 64];
  __shared__ bf16 lB[128 * 64];
  const int t = threadIdx.x;
  const int w = t >> 6, lane = t & 63;
  const int col0 = lane & 15, quad = lane >> 4;
  const int m0 = blockIdx.y * 128, n0 = blockIdx.x * 128;
  const int wr = (w >> 1) * 64, wc = (w & 1) * 64;

  const int lrow = t >> 3;                          // 0..31 (includes w*8)
  const int sswz = (((t & 7) ^ (lrow & 7)) << 3);   // swizzled src k-offset

  f32x4 acc[4][4] = {};

  for (int k0 = 0; k0 < K; k0 += 64) {
    __syncthreads();  // previous iteration's LDS reads done
#pragma unroll
    for (int c = 0; c < 4; ++c) {
      g2lds16(A  + (size_t)(m0 + c * 32 + lrow) * K + k0 + sswz, &lA[c * 2048 + w * 512]);
      g2lds16(Bt + (size_t)(n0 + c * 32 + lrow) * K + k0 + sswz, &lB[c * 2048 + w * 512]);
    }
    __syncthreads();  // drains vmcnt(0): staged tiles visible

#pragma unroll
    for (int kh = 0; kh < 2; ++kh) {
      bf16x8 af[4], bfr[4];
#pragma unroll
      for (int i = 0; i < 4; ++i) {
        int row = wr + i * 16 + col0;
        af[i] = *(const bf16x8*)&lA[row * 64 + (((kh * 4 + quad) ^ (row & 7)) << 3)];
      }
#pragma unroll
      for (int j = 0; j < 4; ++j) {
        int row = wc + j * 16 + col0;
        bfr[j] = *(const bf16x8*)&lB[row * 64 + (((kh * 4 + quad) ^ (row & 7)) << 3)];
      }
#pragma unroll
      for (int i = 0; i < 4; ++i)
#pragma unroll
        for (int j = 0; j < 4; ++j)
          acc[i][j] = __builtin_amdgcn_mfma_f32_16x16x32_bf16(af[i], bfr[j], acc[i][j], 0, 0, 0);
    }
  }

#pragma unroll
  for (int i = 0; i < 4; ++i)
#pragma unroll
    for (int j = 0; j < 4; ++j)
#pragma unroll
      for (int r = 0; r < 4; ++r) {
        int row = m0 + wr + i * 16 + quad * 4 + r;
        int col = n0 + wc + j * 16 + col0;
        C[(size_t)row * N + col] = (OutT)acc[i][j][r];
      }
}

// ---------------------------------------------------------------------------
// Kernel 3b v4: 256x256 GEMM, m201-faithful phase schedule.
// 512 thr = 8 waves (2Mx4N), BK=64, 128 KB LDS dbuf (tile parity).
//
// Per K-tile: 4 phases = 4 INDEPENDENT accumulator bands (band q = C rows
// [q*64,q*64+64); wave wm covers the wm*32 half). No inter-phase acc RAW ->
// each phase's 16 MFMAs ISSUE fast (~64cyc) and execute async; the next
// phase's ds_reads/stages run UNDER the matrix pipe. That async-pipe overlap
// (not instruction reordering) is what R1-R3 structures broke.
//
// Phase shape (m201): {reads(pre-barrier); 2 stage gloads; counted vmcnt;
// barrier; lgkmcnt(0)+sched_barrier; setprio(1); 16 MFMA; setprio(0);
// barrier}. ph0 additionally reads all 8 B frags into regs (held for the
// tile; B traffic once/tile, the R2 win).
//
// Staging (tile T+1 into other buffer, 2 gloads/phase, 8/tile):
//   ph0: A0',B0' | ph1: B1',B2' | ph2: B3',A1' | ph3: A2',A3'
// Ledger (per-thread in-order; outstanding at T.ph0 pre-issue = [A1,A2,A3]):
//   ph0 +[A0',B0'] =5, W=vmcnt(4) drains A1 (issued T-1.ph2, 2 phases old)
//   ph1 +[B1',B2'] =6, W=vmcnt(5) drains A2 (T-1.ph3)
//   ph2 +[B3',A1'] =7, W=vmcnt(6) drains A3 (T-1.ph3)
//   ph3 +[A2',A3'] =8, W=vmcnt(3) drains A0',B0'..B3' (needs of T+1.ph0)
// -> every phase-p read was validated at phase p-1's wait+barrier, so
// pre-barrier read issue is race-free. Never vmcnt(0) in the loop.
// Swizzle: LDS[row][ck] = G[row][ck^(row&7)] via pre-swizzled global source
// (linear LDS dest); reads XOR the same involution. 0-conflict (measured).
// Partial last column tile (N=3200): B row clamp to N-1 (zero pad rows),
// C stores guarded col<N.
// ---------------------------------------------------------------------------
template <typename OutT>
__global__ __launch_bounds__(512, 2) void gemm_bt_256(
    const bf16* __restrict__ A, const bf16* __restrict__ Bt,
    OutT* __restrict__ C, int M, int N, int K) {
  extern __shared__ bf16 lds[];
  bf16* A0 = lds;               // [256][64]
  bf16* B0 = lds + 16384;
  bf16* A1 = lds + 32768;
  bf16* B1 = lds + 49152;

  const int t = threadIdx.x;
  const int w = t >> 6, lane = t & 63;
  const int wm = w >> 2, wn = w & 3;
  const int col0 = lane & 15, quad = lane >> 4;
  const int sswz = (((t & 7) ^ ((t >> 3) & 7)) << 3);  // pre-swizzled src chunk

  // XCD-aware bijective swizzle (requires nwg % 8 == 0; 416 is)
  int nwg = gridDim.x * gridDim.y;
  int bid = blockIdx.y * gridDim.x + blockIdx.x;
  int swz = bid;
  if ((nwg & 7) == 0) swz = (bid & 7) * (nwg >> 3) + (bid >> 3);
  const int n0 = (swz % gridDim.x) * 256;
  const int m0 = (swz / gridDim.x) * 256;

  const bf16* Abase = A + (size_t)m0 * (size_t)K;

  // quarter c = 64 rows; 512 threads x 16B = exactly one quarter per call
  auto stageA = [&](int ks, int c, bf16* dstA) {
    int row = c * 64 + (t >> 3);
    g2lds16(Abase + (size_t)row * K + ks + sswz, dstA + c * 4096 + w * 512);
  };
  auto stageB = [&](int ks, int c, bf16* dstB) {
    int gr = n0 + c * 64 + (t >> 3);
    gr = (gr < N) ? gr : (N - 1);   // clamp: partial tile reads zero-pad row
    g2lds16(Bt + (size_t)gr * (size_t)K + ks + sswz, dstB + c * 4096 + w * 512);
  };

  f32x4 acc[4][2][4] = {};   // [band q][m2][nj]
  const int NT = K >> 6;     // K-tiles (16 for K=1024)

  // ---- prologue: tile 0's 8 loads; order ends A1,A2,A3 (ledger invariant)
  stageB(0, 0, B0); stageB(0, 1, B0); stageB(0, 2, B0); stageB(0, 3, B0);
  stageA(0, 0, A0);
  stageA(0, 1, A0); stageA(0, 2, A0); stageA(0, 3, A0);
  asm volatile("s_waitcnt vmcnt(3)" ::: "memory");  // B(0)+A0(0) landed
  __builtin_amdgcn_s_barrier();

  for (int T = 0; T < NT; ++T) {
    bf16* cA = (T & 1) ? A1 : A0;
    bf16* cB = (T & 1) ? B1 : B0;
    bf16* nA = (T & 1) ? A0 : A1;
    bf16* nB = (T & 1) ? B0 : B1;
    int tn = T + 1;
    int kn = ((tn < NT) ? tn : 0) << 6;  // clamp: tail garbage never read

    bf16x8 bv[4][2];
#pragma unroll
    for (int q = 0; q < 4; ++q) {
      // ---- pre-barrier: reads (validated at previous phase's barrier)
      if (q == 0) {
#pragma unroll
        for (int nj = 0; nj < 4; ++nj) {
          int br = wn * 64 + nj * 16 + col0;
#pragma unroll
          for (int ks = 0; ks < 2; ++ks)
            bv[nj][ks] = *(const bf16x8*)&cB[br * 64 + (((ks * 4 + quad) ^ (br & 7)) << 3)];
        }
      }
      bf16x8 af[2][2];
#pragma unroll
      for (int m2 = 0; m2 < 2; ++m2) {
        int ar = q * 64 + wm * 32 + m2 * 16 + col0;
#pragma unroll
        for (int ks = 0; ks < 2; ++ks)
          af[m2][ks] = *(const bf16x8*)&cA[ar * 64 + (((ks * 4 + quad) ^ (ar & 7)) << 3)];
      }
      // ---- 2 staging gloads/phase (into the other buffer: no WAR)
      if (q == 0)      { stageA(kn, 0, nA); stageB(kn, 0, nB); }
      else if (q == 1) { stageB(kn, 1, nB); stageB(kn, 2, nB); }
      else if (q == 2) { stageB(kn, 3, nB); stageA(kn, 1, nA); }
      else             { stageA(kn, 2, nA); stageA(kn, 3, nA); }
      // ---- counted wait (single-drain, >=2-phase-old targets) + barrier
      if (q == 0)      asm volatile("s_waitcnt vmcnt(4)" ::: "memory");
      else if (q == 1) asm volatile("s_waitcnt vmcnt(5)" ::: "memory");
      else if (q == 2) asm volatile("s_waitcnt vmcnt(6)" ::: "memory");
      else             asm volatile("s_waitcnt vmcnt(3)" ::: "memory");
      __builtin_amdgcn_s_barrier();
      asm volatile("s_waitcnt lgkmcnt(0)" ::: "memory");
      __builtin_amdgcn_sched_barrier(0);
      // ---- 16 MFMA, one independent acc band: issues fast, executes async
      __builtin_amdgcn_s_setprio(1);
#pragma unroll
      for (int ks = 0; ks < 2; ++ks)
#pragma unroll
        for (int m2 = 0; m2 < 2; ++m2)
#pragma unroll
          for (int nj = 0; nj < 4; ++nj)
            acc[q][m2][nj] = __builtin_amdgcn_mfma_f32_16x16x32_bf16(
                af[m2][ks], bv[nj][ks], acc[q][m2][nj], 0, 0, 0);
      __builtin_amdgcn_s_setprio(0);
      __builtin_amdgcn_s_barrier();
    }
  }
  // drain tail garbage stages before wave exit (LDS could be reassigned)
  asm volatile("s_waitcnt vmcnt(0)" ::: "memory");

  // epilogue: band q rows = m0 + q*64 + wm*32 + m2*16 + quad*4 + r
#pragma unroll
  for (int q = 0; q < 4; ++q)
#pragma unroll
    for (int m2 = 0; m2 < 2; ++m2)
#pragma unroll
      for (int nj = 0; nj < 4; ++nj) {
        int col = n0 + wn * 64 + nj * 16 + col0;
        if (col < N) {
          size_t base = (size_t)(m0 + q * 64 + wm * 32 + m2 * 16 + quad * 4) * N + col;
#pragma unroll
          for (int r = 0; r < 4; ++r)
            C[base + (size_t)r * N] = (OutT)acc[q][m2][nj][r];
        }
      }
}

// ---------------------------------------------------------------------------
// Kernel 4: sliding-window attention, one block per (b, h, 64-query group).
// ---------------------------------------------------------------------------
#define NEG_BIG -1e30f
__global__ __launch_bounds__(256) void attn_kernel(
    const bf16* __restrict__ qkv, const float* __restrict__ bg,
    bf16* __restrict__ attnO) {
  __shared__ bf16 lQ[64 * 64];     // 8 KB,  swizzled chunks
  __shared__ bf16 lKV[320 * 64];   // 40 KB: K[320][64] phase1, Vt[64][320] phase2
  __shared__ bf16 lP[4 * 16 * 32]; // 4 KB: per-wave P C->A layout scratch

  const int t = threadIdx.x;
  const int w = t >> 6, lane = t & 63;
  const int col0 = lane & 15, quad = lane >> 4;

  const int blk = blockIdx.x;
  const int g = blk & 63;
  const int h = (blk >> 6) & 15;
  const int bb = blk >> 10;
  const int qs = g * 64;

  const size_t rs = 3200;
  const bf16* qbase = qkv + ((size_t)bb * 4096) * rs + h * 64;

  // stage Q [64][64], chunk-swizzled: LDS[row][ck^(row&7)] = G[row][ck]
  for (int c = t; c < 64 * 8; c += 256) {
    int row = c >> 3, ck = c & 7;
    *(uint4*)&lQ[row * 64 + ((ck ^ (row & 7)) << 3)] =
        *(const uint4*)(qbase + (size_t)(qs + row) * rs + ck * 8);
  }
  // stage K [320][64], chunk-swizzled (zero-fill j<0)
  for (int c = t; c < 320 * 8; c += 256) {
    int row = c >> 3, ck = c & 7;
    int j = qs - 256 + row;
    uint4 val = {0, 0, 0, 0};
    if (j >= 0) val = *(const uint4*)(qbase + 1024 + (size_t)j * rs + ck * 8);
    *(uint4*)&lKV[row * 64 + ((ck ^ (row & 7)) << 3)] = val;
  }
  __syncthreads();

  // QK^T: wave w owns queries [w*16, w*16+16); S tile per wave: [16, 320]
  const int qrow = w * 16 + col0;
  bf16x8 a0 = *(const bf16x8*)&lQ[qrow * 64 + ((quad ^ (qrow & 7)) << 3)];
  bf16x8 a1 = *(const bf16x8*)&lQ[qrow * 64 + (((4 + quad) ^ (qrow & 7)) << 3)];
  f32x4 s[20];
#pragma unroll
  for (int kt = 0; kt < 20; ++kt) {
    int krow = kt * 16 + col0;
    bf16x8 b0 = *(const bf16x8*)&lKV[krow * 64 + ((quad ^ (krow & 7)) << 3)];
    bf16x8 b1 = *(const bf16x8*)&lKV[krow * 64 + (((4 + quad) ^ (krow & 7)) << 3)];
    f32x4 z = {};
    z = __builtin_amdgcn_mfma_f32_16x16x32_bf16(a0, b0, z, 0, 0, 0);
    z = __builtin_amdgcn_mfma_f32_16x16x32_bf16(a1, b1, z, 0, 0, 0);
    s[kt] = z;
  }
  __syncthreads();  // all waves done reading K from lKV

  // stage V transposed Vt[d][c] over lKV, key-major lanes + chunk swizzle
  {
    const int jl = t & 31, dg = t >> 5;
#pragma unroll
    for (int cc = 0; cc < 10; ++cc) {
      int j = qs - 256 + cc * 32 + jl;
      bf16 tmp[8];
      if (j >= 0) {
        *(uint4*)tmp = *(const uint4*)(qbase + 2048 + (size_t)j * rs + dg * 8);
      } else {
#pragma unroll
        for (int d2 = 0; d2 < 8; ++d2) tmp[d2] = (bf16)0.f;
      }
      int ck = cc * 4 + (jl >> 3);     // 16B chunk index along keys (0..39)
      int wi = jl & 7;                 // element within chunk
#pragma unroll
      for (int d2 = 0; d2 < 8; ++d2) {
        int d = dg * 8 + d2;
        lKV[d * 320 + ((ck ^ (d & 7)) << 3) + wi] = tmp[d2];
      }
    }
  }

  // softmax in registers (C layout: query row = quad*4+r, key col = kt*16+col0)
  float mrow[4] = {NEG_BIG, NEG_BIG, NEG_BIG, NEG_BIG};
  float lrow[4] = {0, 0, 0, 0};
#pragma unroll
  for (int kt = 0; kt < 20; ++kt) {
    int c = kt * 16 + col0;
#pragma unroll
    for (int r = 0; r < 4; ++r) {
      int ql = w * 16 + quad * 4 + r;
      bool valid = (c >= ql) && (c <= ql + 256) && (qs - 256 + c >= 0);
      float sv = valid ? s[kt][r] * 0.125f : NEG_BIG;  // scale = 1/sqrt(64)
      s[kt][r] = sv;
      mrow[r] = fmaxf(mrow[r], sv);
    }
  }
#pragma unroll
  for (int mm = 1; mm < 16; mm <<= 1)
#pragma unroll
    for (int r = 0; r < 4; ++r) mrow[r] = fmaxf(mrow[r], __shfl_xor(mrow[r], mm));
#pragma unroll
  for (int kt = 0; kt < 20; ++kt)
#pragma unroll
    for (int r = 0; r < 4; ++r) {
      float p = __expf(s[kt][r] - mrow[r]);
      s[kt][r] = p;
      lrow[r] += p;
    }
#pragma unroll
  for (int mm = 1; mm < 16; mm <<= 1)
#pragma unroll
    for (int r = 0; r < 4; ++r) lrow[r] += __shfl_xor(lrow[r], mm);

  __syncthreads();  // Vt staged

  // PV: per 32-key chunk, C->A transpose of P through per-wave LDS scratch.
  f32x4 o[4] = {};
  bf16* pw = &lP[w * 512];
#pragma unroll
  for (int kc = 0; kc < 10; ++kc) {
#pragma unroll
    for (int r = 0; r < 4; ++r) {
      pw[(quad * 4 + r) * 32 + col0]      = (bf16)s[2 * kc][r];
      pw[(quad * 4 + r) * 32 + 16 + col0] = (bf16)s[2 * kc + 1][r];
    }
    asm volatile("s_waitcnt lgkmcnt(0)" ::: "memory");
    bf16x8 pa = *(const bf16x8*)&pw[col0 * 32 + quad * 8];
#pragma unroll
    for (int n = 0; n < 4; ++n) {
      int d = n * 16 + col0;
      bf16x8 bvv = *(const bf16x8*)&lKV[d * 320 + (((kc * 4 + quad) ^ (d & 7)) << 3)];
      o[n] = __builtin_amdgcn_mfma_f32_16x16x32_bf16(pa, bvv, o[n], 0, 0, 0);
    }
  }

  // epilogue: divide by l, apply sigmoid(gate_logit + bg[h]), write [b,s,h*64+d]
  const bf16* gbase = qkv + ((size_t)bb * 4096) * rs + 3072 + h;
  const float bgh = bg[h];
#pragma unroll
  for (int r = 0; r < 4; ++r) {
    int ql = w * 16 + quad * 4 + r;
    int srow = qs + ql;
    float logit = (float)gbase[(size_t)srow * rs] + bgh;
    float gate = 1.f / (1.f + __expf(-logit));
    float scale = gate / lrow[r];
#pragma unroll
    for (int n = 0; n < 4; ++n)
      attnO[((size_t)bb * 4096 + srow) * 1024 + h * 64 + n * 16 + col0] =
          (bf16)(o[n][r] * scale);
  }
}

// ---------------------------------------------------------------------------
extern "C" void kernel_launch(void* const* d_in, const int* in_sizes, int n_in,
                              void* d_out, int out_size, void* d_ws, size_t ws_size,
                              hipStream_t stream) {
  const float *x = nullptr, *gamma = nullptr, *Wqkv = nullptr,
              *Wg = nullptr, *bg = nullptr, *Wout = nullptr;
  for (int i = 0; i < n_in; ++i) {
    switch (in_sizes[i]) {
      case 8388608: x     = (const float*)d_in[i]; break;
      case 1024:    gamma = (const float*)d_in[i]; break;
      case 3145728: Wqkv  = (const float*)d_in[i]; break;
      case 16384:   Wg    = (const float*)d_in[i]; break;
      case 16:      bg    = (const float*)d_in[i]; break;
      case 1048576: Wout  = (const float*)d_in[i]; break;
    }
  }
  float* out = (float*)d_out;  // fp32 output

  // one-time: allow 128 KB dynamic LDS for the 256^2 GEMM
  static bool attr_done = false;
  if (!attr_done) {
    hipFuncSetAttribute(reinterpret_cast<const void*>(&gemm_bt_256<bf16>),
                        hipFuncAttributeMaxDynamicSharedMemorySize, 131072);
    attr_done = true;
  }

  // BtAug = [WqkvT (3072 rows); WgT (16 rows); zero pad (112 rows)] x 1024
  char* ws = (char*)d_ws;
  bf16* qkv   = (bf16*)ws;  ws += (size_t)8192 * 3200 * 2;   // 52.4 MB (incl. gate logits)
  bf16* xn    = (bf16*)ws;                                    // 16 MB, dead after QKV GEMM
  bf16* attnO = (bf16*)ws;  ws += (size_t)8192 * 1024 * 2;   // aliases xn (stream-ordered)
  bf16* BtAug = (bf16*)ws;  ws += (size_t)3200 * 1024 * 2;   // 6.55 MB
  bf16* WoutT = (bf16*)ws;  ws += (size_t)1024 * 1024 * 2;   // total ~77.9 MB

  // zero the 112 pad rows of BtAug (re-poisoned to 0xAA before every call)
  hipMemsetAsync(BtAug + (size_t)3088 * 1024, 0, (size_t)112 * 1024 * 2, stream);

  rmsnorm_kernel<<<8192, 256, 0, stream>>>(x, gamma, xn);
  transpose_f32_bf16<<<dim3(3072 / 32, 1024 / 32), dim3(32, 8), 0, stream>>>(Wqkv, BtAug, 1024, 3072);
  wg_transpose<<<64, 256, 0, stream>>>(Wg, BtAug);
  transpose_f32_bf16<<<dim3(1024 / 32, 1024 / 32), dim3(32, 8), 0, stream>>>(Wout, WoutT, 1024, 1024);
  // QKV GEMM: 256^2, grid 13x32 = 416 (nwg%8==0 -> XCD swizzle valid)
  gemm_bt_256<bf16><<<dim3(13, 32), 512, 131072, stream>>>(xn, BtAug, qkv, 8192, 3200, 1024);
  attn_kernel<<<2048, 256, 0, stream>>>(qkv, bg, attnO);
  gemm_bt_128<float><<<dim3(1024 / 128, 8192 / 128), 256, 0, stream>>>(attnO, WoutT, out, 8192, 1024, 1024);
}

// Round 5
// 235.148 us; speedup vs baseline: 1.0974x; 1.0952x over previous
//
#include <hip/hip_runtime.h>
#include <hip/hip_bf16.h>
#include <stdint.h>

typedef __bf16 bf16;
typedef __bf16 bf16x4 __attribute__((ext_vector_type(4)));
typedef __bf16 bf16x8 __attribute__((ext_vector_type(8)));
typedef float f32x4 __attribute__((ext_vector_type(4)));

#define GLOBAL_AS __attribute__((address_space(1)))
#define LDS_AS __attribute__((address_space(3)))

__device__ __forceinline__ void g2lds16(const bf16* g, bf16* l) {
  // async global->LDS DMA, 16 B/lane; LDS dest = wave-uniform base + lane*16
  __builtin_amdgcn_global_load_lds((const GLOBAL_AS void*)g, (LDS_AS void*)l, 16, 0, 0);
}

// ---------------------------------------------------------------------------
// Kernel 1: pure streaming RMSNorm (F.normalize * sqrt(1024) * gamma).
// ---------------------------------------------------------------------------
__global__ __launch_bounds__(256) void rmsnorm_kernel(
    const float* __restrict__ x, const float* __restrict__ gamma,
    bf16* __restrict__ xn) {
  __shared__ float wss[4];
  const int t = threadIdx.x;
  const size_t row = blockIdx.x;
  const float* xr = x + row * 1024;

  float4 xv = *(const float4*)&xr[t * 4];
  float v[4] = {xv.x, xv.y, xv.z, xv.w};
  float ss = v[0]*v[0] + v[1]*v[1] + v[2]*v[2] + v[3]*v[3];
#pragma unroll
  for (int mm = 1; mm < 64; mm <<= 1) ss += __shfl_xor(ss, mm);
  if ((t & 63) == 0) wss[t >> 6] = ss;
  __syncthreads();
  ss = wss[0] + wss[1] + wss[2] + wss[3];
  float inv = 32.0f / sqrtf(fmaxf(ss, 1e-24f));  // sqrt(1024)=32

  float4 gv = *(const float4*)&gamma[t * 4];
  float gvv[4] = {gv.x, gv.y, gv.z, gv.w};
  bf16x4 outv;
#pragma unroll
  for (int i = 0; i < 4; ++i) outv[i] = (bf16)(v[i] * inv * gvv[i]);
  *(bf16x4*)&xn[row * 1024 + t * 4] = outv;
}

// ---------------------------------------------------------------------------
// Kernel 2: fp32 -> bf16 transpose (for B^T GEMM operand), 32x32 tiles
// ---------------------------------------------------------------------------
__global__ void transpose_f32_bf16(const float* __restrict__ in, bf16* __restrict__ out,
                                   int R, int C) {
  __shared__ bf16 tile[32][33];
  const int tx = threadIdx.x, ty = threadIdx.y;  // 32 x 8
  const int c0 = blockIdx.x * 32, r0 = blockIdx.y * 32;
#pragma unroll
  for (int i = 0; i < 32; i += 8)
    tile[ty + i][tx] = (bf16)in[(size_t)(r0 + ty + i) * C + c0 + tx];
  __syncthreads();
#pragma unroll
  for (int i = 0; i < 32; i += 8)
    out[(size_t)(c0 + ty + i) * R + r0 + tx] = tile[tx][ty + i];
}

// Wg [1024,16] -> rows 3072..3087 of BtAug [3200,1024]. Tiny (16K elements).
__global__ __launch_bounds__(256) void wg_transpose(const float* __restrict__ Wg,
                                                    bf16* __restrict__ BtAug) {
  int idx = blockIdx.x * 256 + threadIdx.x;   // [0, 16384)
  int n = idx >> 10, k = idx & 1023;
  BtAug[(size_t)(3072 + n) * 1024 + k] = (bf16)Wg[(size_t)k * 16 + n];
}

// ---------------------------------------------------------------------------
// Kernel 3a: MFMA bf16 GEMM, 128x128 tile, BK=64, 2-barrier structure.
// Kept for the output GEMM (N=1024: 512-block grid balances the GPU).
// ---------------------------------------------------------------------------
template <typename OutT>
__global__ __launch_bounds__(256) void gemm_bt_128(
    const bf16* __restrict__ A, const bf16* __restrict__ Bt,
    OutT* __restrict__ C, int M, int N, int K) {
  __shared__ bf16 lA[128 * 64];
  __shared__ bf16 lB[128 * 64];
  const int t = threadIdx.x;
  const int w = t >> 6, lane = t & 63;
  const int col0 = lane & 15, quad = lane >> 4;
  const int m0 = blockIdx.y * 128, n0 = blockIdx.x * 128;
  const int wr = (w >> 1) * 64, wc = (w & 1) * 64;

  const int lrow = t >> 3;                          // 0..31 (includes w*8)
  const int sswz = (((t & 7) ^ (lrow & 7)) << 3);   // swizzled src k-offset

  f32x4 acc[4][4] = {};

  for (int k0 = 0; k0 < K; k0 += 64) {
    __syncthreads();  // previous iteration's LDS reads done
#pragma unroll
    for (int c = 0; c < 4; ++c) {
      g2lds16(A  + (size_t)(m0 + c * 32 + lrow) * K + k0 + sswz, &lA[c * 2048 + w * 512]);
      g2lds16(Bt + (size_t)(n0 + c * 32 + lrow) * K + k0 + sswz, &lB[c * 2048 + w * 512]);
    }
    __syncthreads();  // drains vmcnt(0): staged tiles visible

#pragma unroll
    for (int kh = 0; kh < 2; ++kh) {
      bf16x8 af[4], bfr[4];
#pragma unroll
      for (int i = 0; i < 4; ++i) {
        int row = wr + i * 16 + col0;
        af[i] = *(const bf16x8*)&lA[row * 64 + (((kh * 4 + quad) ^ (row & 7)) << 3)];
      }
#pragma unroll
      for (int j = 0; j < 4; ++j) {
        int row = wc + j * 16 + col0;
        bfr[j] = *(const bf16x8*)&lB[row * 64 + (((kh * 4 + quad) ^ (row & 7)) << 3)];
      }
#pragma unroll
      for (int i = 0; i < 4; ++i)
#pragma unroll
        for (int j = 0; j < 4; ++j)
          acc[i][j] = __builtin_amdgcn_mfma_f32_16x16x32_bf16(af[i], bfr[j], acc[i][j], 0, 0, 0);
    }
  }

#pragma unroll
  for (int i = 0; i < 4; ++i)
#pragma unroll
    for (int j = 0; j < 4; ++j)
#pragma unroll
      for (int r = 0; r < 4; ++r) {
        int row = m0 + wr + i * 16 + quad * 4 + r;
        int col = n0 + wc + j * 16 + col0;
        C[(size_t)row * N + col] = (OutT)acc[i][j][r];
      }
}

// ---------------------------------------------------------------------------
// Kernel 3b v4: 256x256 GEMM, phase schedule (unchanged from R3->R4).
// ---------------------------------------------------------------------------
template <typename OutT>
__global__ __launch_bounds__(512, 2) void gemm_bt_256(
    const bf16* __restrict__ A, const bf16* __restrict__ Bt,
    OutT* __restrict__ C, int M, int N, int K) {
  extern __shared__ bf16 lds[];
  bf16* A0 = lds;               // [256][64]
  bf16* B0 = lds + 16384;
  bf16* A1 = lds + 32768;
  bf16* B1 = lds + 49152;

  const int t = threadIdx.x;
  const int w = t >> 6, lane = t & 63;
  const int wm = w >> 2, wn = w & 3;
  const int col0 = lane & 15, quad = lane >> 4;
  const int sswz = (((t & 7) ^ ((t >> 3) & 7)) << 3);  // pre-swizzled src chunk

  // XCD-aware bijective swizzle (requires nwg % 8 == 0; 416 is)
  int nwg = gridDim.x * gridDim.y;
  int bid = blockIdx.y * gridDim.x + blockIdx.x;
  int swz = bid;
  if ((nwg & 7) == 0) swz = (bid & 7) * (nwg >> 3) + (bid >> 3);
  const int n0 = (swz % gridDim.x) * 256;
  const int m0 = (swz / gridDim.x) * 256;

  const bf16* Abase = A + (size_t)m0 * (size_t)K;

  auto stageA = [&](int ks, int c, bf16* dstA) {
    int row = c * 64 + (t >> 3);
    g2lds16(Abase + (size_t)row * K + ks + sswz, dstA + c * 4096 + w * 512);
  };
  auto stageB = [&](int ks, int c, bf16* dstB) {
    int gr = n0 + c * 64 + (t >> 3);
    gr = (gr < N) ? gr : (N - 1);   // clamp: partial tile reads zero-pad row
    g2lds16(Bt + (size_t)gr * (size_t)K + ks + sswz, dstB + c * 4096 + w * 512);
  };

  f32x4 acc[4][2][4] = {};   // [band q][m2][nj]
  const int NT = K >> 6;     // K-tiles (16 for K=1024)

  stageB(0, 0, B0); stageB(0, 1, B0); stageB(0, 2, B0); stageB(0, 3, B0);
  stageA(0, 0, A0);
  stageA(0, 1, A0); stageA(0, 2, A0); stageA(0, 3, A0);
  asm volatile("s_waitcnt vmcnt(3)" ::: "memory");  // B(0)+A0(0) landed
  __builtin_amdgcn_s_barrier();

  for (int T = 0; T < NT; ++T) {
    bf16* cA = (T & 1) ? A1 : A0;
    bf16* cB = (T & 1) ? B1 : B0;
    bf16* nA = (T & 1) ? A0 : A1;
    bf16* nB = (T & 1) ? B0 : B1;
    int tn = T + 1;
    int kn = ((tn < NT) ? tn : 0) << 6;  // clamp: tail garbage never read

    bf16x8 bv[4][2];
#pragma unroll
    for (int q = 0; q < 4; ++q) {
      if (q == 0) {
#pragma unroll
        for (int nj = 0; nj < 4; ++nj) {
          int br = wn * 64 + nj * 16 + col0;
#pragma unroll
          for (int ks = 0; ks < 2; ++ks)
            bv[nj][ks] = *(const bf16x8*)&cB[br * 64 + (((ks * 4 + quad) ^ (br & 7)) << 3)];
        }
      }
      bf16x8 af[2][2];
#pragma unroll
      for (int m2 = 0; m2 < 2; ++m2) {
        int ar = q * 64 + wm * 32 + m2 * 16 + col0;
#pragma unroll
        for (int ks = 0; ks < 2; ++ks)
          af[m2][ks] = *(const bf16x8*)&cA[ar * 64 + (((ks * 4 + quad) ^ (ar & 7)) << 3)];
      }
      if (q == 0)      { stageA(kn, 0, nA); stageB(kn, 0, nB); }
      else if (q == 1) { stageB(kn, 1, nB); stageB(kn, 2, nB); }
      else if (q == 2) { stageB(kn, 3, nB); stageA(kn, 1, nA); }
      else             { stageA(kn, 2, nA); stageA(kn, 3, nA); }
      if (q == 0)      asm volatile("s_waitcnt vmcnt(4)" ::: "memory");
      else if (q == 1) asm volatile("s_waitcnt vmcnt(5)" ::: "memory");
      else if (q == 2) asm volatile("s_waitcnt vmcnt(6)" ::: "memory");
      else             asm volatile("s_waitcnt vmcnt(3)" ::: "memory");
      __builtin_amdgcn_s_barrier();
      asm volatile("s_waitcnt lgkmcnt(0)" ::: "memory");
      __builtin_amdgcn_sched_barrier(0);
      __builtin_amdgcn_s_setprio(1);
#pragma unroll
      for (int ks = 0; ks < 2; ++ks)
#pragma unroll
        for (int m2 = 0; m2 < 2; ++m2)
#pragma unroll
          for (int nj = 0; nj < 4; ++nj)
            acc[q][m2][nj] = __builtin_amdgcn_mfma_f32_16x16x32_bf16(
                af[m2][ks], bv[nj][ks], acc[q][m2][nj], 0, 0, 0);
      __builtin_amdgcn_s_setprio(0);
      __builtin_amdgcn_s_barrier();
    }
  }
  asm volatile("s_waitcnt vmcnt(0)" ::: "memory");

#pragma unroll
  for (int q = 0; q < 4; ++q)
#pragma unroll
    for (int m2 = 0; m2 < 2; ++m2)
#pragma unroll
      for (int nj = 0; nj < 4; ++nj) {
        int col = n0 + wn * 64 + nj * 16 + col0;
        if (col < N) {
          size_t base = (size_t)(m0 + q * 64 + wm * 32 + m2 * 16 + quad * 4) * N + col;
#pragma unroll
          for (int r = 0; r < 4; ++r)
            C[base + (size_t)r * N] = (OutT)acc[q][m2][nj][r];
        }
      }
}

// ---------------------------------------------------------------------------
// Kernel 4 v5: sliding-window attention, swapped-operand form.
// One block per (b, h, 64-query group); 4 waves x 16 queries.
// LDS = exactly 40 KB (K tile, V^T overlaid) -> 4 blocks/CU.
// QK^T = mfma(K, Q^T): lane owns ALL scores of one query (q = lane&15,
//   k spread over quads) -> softmax = 80 local ops + 2 shfl rounds.
// PV = mfma(V^T, P): P goes C-layout -> B-layout fully in registers
//   (4x cvt_pk + 8x shfl per 32-key chunk) -- no lP, no lgkm drains,
//   no 8-way-conflict writes (the R4 counter's 1.64M conflicts).
// K staged by global_load_lds w/ pre-swizzled source; j<0 rows clamp to
//   row 0: finite garbage, masked to NEG_BIG before any use; P=0 for
//   masked keys kills garbage V in PV (0xAA poison = finite bf16).
// XCD-chunked bid swizzle: consecutive g share 256/320 keys -> L2 hits.
// ---------------------------------------------------------------------------
#define NEG_BIG -1e30f
__global__ __launch_bounds__(256, 4) void attn_kernel(
    const bf16* __restrict__ qkv, const float* __restrict__ bg,
    bf16* __restrict__ attnO) {
  __shared__ bf16 lKV[320 * 64];   // 40 KB: K[320][64] ph1, Vt[64][320] ph2

  const int t = threadIdx.x;
  const int lane = t & 63;
  const int w = t >> 6;
  const int col0 = lane & 15, quad = lane >> 4;

  const int bid = blockIdx.x;
  const int blk = ((bid & 7) << 8) | (bid >> 3);   // XCD-chunked (2048 % 8 == 0)
  const int g = blk & 63;
  const int h = (blk >> 6) & 15;
  const int bb = blk >> 10;
  const int qs = g * 64;

  const size_t rs = 3200;
  const bf16* qbase = qkv + ((size_t)bb * 4096) * rs + h * 64;

  // ---- stage K[320][64] via async DMA (chunk-swizzled via source)
  {
    const int lr = t >> 3;                          // 0..31 (includes w*8)
    const int sswz = ((t & 7) ^ (lr & 7)) << 3;
#pragma unroll
    for (int c = 0; c < 10; ++c) {
      int j = qs - 256 + c * 32 + lr;
      j = (j < 0) ? 0 : j;                          // clamp: masked later
      g2lds16(qbase + 1024 + (size_t)j * rs + sswz, &lKV[c * 2048 + w * 512]);
    }
  }
  __builtin_amdgcn_sched_barrier(0);
  // ---- Q B-operand frags + gate logit direct from global (no LDS)
  const int ql = w * 16 + col0;                     // local query index
  const int srow = qs + ql;
  const bf16x8 bq0 = *(const bf16x8*)(qbase + (size_t)srow * rs + quad * 8);
  const bf16x8 bq1 = *(const bf16x8*)(qbase + (size_t)srow * rs + 32 + quad * 8);
  const float logit = (float)qkv[((size_t)bb * 4096 + srow) * rs + 3072 + h];
  asm volatile("s_waitcnt vmcnt(3)" ::: "memory");  // the 10 K DMAs done
  asm volatile("s_barrier" ::: "memory");

  // ---- QK^T swapped: z[kt] rows k = kt*16+quad*4+r, col q = col0
  f32x4 z[20];
#pragma unroll
  for (int kt = 0; kt < 20; ++kt) {
    const int kr = kt * 16 + col0;
    bf16x8 a0 = *(const bf16x8*)&lKV[kr * 64 + ((quad ^ (kr & 7)) << 3)];
    bf16x8 a1 = *(const bf16x8*)&lKV[kr * 64 + (((4 + quad) ^ (kr & 7)) << 3)];
    f32x4 zz = {};
    zz = __builtin_amdgcn_mfma_f32_16x16x32_bf16(a0, bq0, zz, 0, 0, 0);
    zz = __builtin_amdgcn_mfma_f32_16x16x32_bf16(a1, bq1, zz, 0, 0, 0);
    z[kt] = zz;
  }
  asm volatile("s_barrier" ::: "memory");           // all waves done reading K

  // ---- V -> Vt[64][320] overlay (key-major lanes, 2-way-free chunk swizzle)
  {
    const int jl = t & 31, dg = t >> 5;
#pragma unroll
    for (int cc = 0; cc < 10; ++cc) {
      int j = qs - 256 + cc * 32 + jl;
      j = (j < 0) ? 0 : j;                          // finite garbage; P=0 there
      bf16 tmp[8];
      *(uint4*)tmp = *(const uint4*)(qbase + 2048 + (size_t)j * rs + dg * 8);
      const int ck = cc * 4 + (jl >> 3);
      const int wi = jl & 7;
#pragma unroll
      for (int d2 = 0; d2 < 8; ++d2) {
        const int d = dg * 8 + d2;
        lKV[d * 320 + ((ck ^ (d & 7)) << 3) + wi] = tmp[d2];
      }
    }
  }

  // ---- softmax: lane owns 80 scores of ONE query; 2 shfl rounds per reduce
  float m = NEG_BIG;
#pragma unroll
  for (int kt = 0; kt < 20; ++kt)
#pragma unroll
    for (int r = 0; r < 4; ++r) {
      const int c = kt * 16 + quad * 4 + r;
      const bool valid = (c >= ql) && (c <= ql + 256) && (qs - 256 + c >= 0);
      const float sv = valid ? z[kt][r] * 0.125f : NEG_BIG;  // 1/sqrt(64)
      z[kt][r] = sv;
      m = fmaxf(m, sv);
    }
  m = fmaxf(m, __shfl_xor(m, 16));
  m = fmaxf(m, __shfl_xor(m, 32));
  float l = 0.f;
#pragma unroll
  for (int kt = 0; kt < 20; ++kt)
#pragma unroll
    for (int r = 0; r < 4; ++r) {
      const float p = __expf(z[kt][r] - m);
      z[kt][r] = p;
      l += p;
    }
  l += __shfl_xor(l, 16);
  l += __shfl_xor(l, 32);

  __syncthreads();                                  // Vt visible

  // ---- PV swapped: o[n] = O^T d-band; P transposed in-register.
  // dest quad d needs k-offsets d*8+j: j<4 from srcquad 2(d&1) (words P*0),
  // j>=4 from srcquad 2(d&1)+1 (words P*1); hi half (d>=2) from kt=2kc+1.
  f32x4 o[4] = {};
  const int sl0 = col0 + ((quad & 1) << 5);
  const bool hi = quad >= 2;
#pragma unroll
  for (int kc = 0; kc < 10; ++kc) {
    uint32_t Pl0, Pl1, Ph0, Ph1;
    asm("v_cvt_pk_bf16_f32 %0, %1, %2" : "=v"(Pl0) : "v"(z[2*kc][0]),   "v"(z[2*kc][1]));
    asm("v_cvt_pk_bf16_f32 %0, %1, %2" : "=v"(Pl1) : "v"(z[2*kc][2]),   "v"(z[2*kc][3]));
    asm("v_cvt_pk_bf16_f32 %0, %1, %2" : "=v"(Ph0) : "v"(z[2*kc+1][0]), "v"(z[2*kc+1][1]));
    asm("v_cvt_pk_bf16_f32 %0, %1, %2" : "=v"(Ph1) : "v"(z[2*kc+1][2]), "v"(z[2*kc+1][3]));
    uint32_t w0l = __shfl((int)Pl0, sl0),      w0h = __shfl((int)Ph0, sl0);
    uint32_t w1l = __shfl((int)Pl1, sl0),      w1h = __shfl((int)Ph1, sl0);
    uint32_t w2l = __shfl((int)Pl0, sl0 + 16), w2h = __shfl((int)Ph0, sl0 + 16);
    uint32_t w3l = __shfl((int)Pl1, sl0 + 16), w3h = __shfl((int)Ph1, sl0 + 16);
    union { uint32_t u[4]; bf16x8 v; } pu;
    pu.u[0] = hi ? w0h : w0l;
    pu.u[1] = hi ? w1h : w1l;
    pu.u[2] = hi ? w2h : w2l;
    pu.u[3] = hi ? w3h : w3l;
#pragma unroll
    for (int n = 0; n < 4; ++n) {
      const int d = n * 16 + col0;
      bf16x8 av = *(const bf16x8*)&lKV[d * 320 + (((kc * 4 + quad) ^ (d & 7)) << 3)];
      o[n] = __builtin_amdgcn_mfma_f32_16x16x32_bf16(av, pu.v, o[n], 0, 0, 0);
    }
  }

  // ---- epilogue: one query per lane; o rows are d = n*16+quad*4+r
  const float gate = 1.f / (1.f + __expf(-(logit + bg[h])));
  const float scale = gate / l;
  bf16* obase = attnO + ((size_t)bb * 4096 + srow) * 1024 + h * 64;
#pragma unroll
  for (int n = 0; n < 4; ++n) {
    bf16x4 ov;
#pragma unroll
    for (int r = 0; r < 4; ++r) ov[r] = (bf16)(o[n][r] * scale);
    *(bf16x4*)&obase[n * 16 + quad * 4] = ov;
  }
}

// ---------------------------------------------------------------------------
extern "C" void kernel_launch(void* const* d_in, const int* in_sizes, int n_in,
                              void* d_out, int out_size, void* d_ws, size_t ws_size,
                              hipStream_t stream) {
  const float *x = nullptr, *gamma = nullptr, *Wqkv = nullptr,
              *Wg = nullptr, *bg = nullptr, *Wout = nullptr;
  for (int i = 0; i < n_in; ++i) {
    switch (in_sizes[i]) {
      case 8388608: x     = (const float*)d_in[i]; break;
      case 1024:    gamma = (const float*)d_in[i]; break;
      case 3145728: Wqkv  = (const float*)d_in[i]; break;
      case 16384:   Wg    = (const float*)d_in[i]; break;
      case 16:      bg    = (const float*)d_in[i]; break;
      case 1048576: Wout  = (const float*)d_in[i]; break;
    }
  }
  float* out = (float*)d_out;  // fp32 output

  // one-time: allow 128 KB dynamic LDS for the 256^2 GEMM
  static bool attr_done = false;
  if (!attr_done) {
    hipFuncSetAttribute(reinterpret_cast<const void*>(&gemm_bt_256<bf16>),
                        hipFuncAttributeMaxDynamicSharedMemorySize, 131072);
    attr_done = true;
  }

  // BtAug = [WqkvT (3072 rows); WgT (16 rows); zero pad (112 rows)] x 1024
  char* ws = (char*)d_ws;
  bf16* qkv   = (bf16*)ws;  ws += (size_t)8192 * 3200 * 2;   // 52.4 MB (incl. gate logits)
  bf16* xn    = (bf16*)ws;                                    // 16 MB, dead after QKV GEMM
  bf16* attnO = (bf16*)ws;  ws += (size_t)8192 * 1024 * 2;   // aliases xn (stream-ordered)
  bf16* BtAug = (bf16*)ws;  ws += (size_t)3200 * 1024 * 2;   // 6.55 MB
  bf16* WoutT = (bf16*)ws;  ws += (size_t)1024 * 1024 * 2;   // total ~77.9 MB

  // zero the 112 pad rows of BtAug (re-poisoned to 0xAA before every call)
  hipMemsetAsync(BtAug + (size_t)3088 * 1024, 0, (size_t)112 * 1024 * 2, stream);

  rmsnorm_kernel<<<8192, 256, 0, stream>>>(x, gamma, xn);
  transpose_f32_bf16<<<dim3(3072 / 32, 1024 / 32), dim3(32, 8), 0, stream>>>(Wqkv, BtAug, 1024, 3072);
  wg_transpose<<<64, 256, 0, stream>>>(Wg, BtAug);
  transpose_f32_bf16<<<dim3(1024 / 32, 1024 / 32), dim3(32, 8), 0, stream>>>(Wout, WoutT, 1024, 1024);
  // QKV GEMM: 256^2, grid 13x32 = 416 (nwg%8==0 -> XCD swizzle valid)
  gemm_bt_256<bf16><<<dim3(13, 32), 512, 131072, stream>>>(xn, BtAug, qkv, 8192, 3200, 1024);
  attn_kernel<<<2048, 256, 0, stream>>>(qkv, bg, attnO);
  gemm_bt_128<float><<<dim3(1024 / 128, 8192 / 128), 256, 0, stream>>>(attnO, WoutT, out, 8192, 1024, 1024);
}